// Round 5
// baseline (1035.415 us; speedup 1.0000x reference)
//
#include <hip/hip_runtime.h>
#include <hip/hip_cooperative_groups.h>

namespace cg = cooperative_groups;

constexpr int N     = 3072;
constexpr int S     = 32;
constexpr int E     = 4;
constexpr int FIN   = 64;
constexpr int CAP   = 64;     // max sources per (e,n); Binomial(3072,0.005) mean 15.4, P(>=64)~1e-19
constexpr int NNi   = N * N;  // 9,437,184
constexpr int DUMMY = N;      // extra all-zero h row for gather padding
constexpr int BLK   = 384;    // coop grid; capacity 2 blocks/CU * 256 CU = 512 >= 384 (margin 128)
constexpr int TPB   = 512;    // 8 waves = 8 nodes per block; 384*8 = 3072

__device__ __forceinline__ float rl(float v, int lane) {   // wave-uniform broadcast via VALU
    return __int_as_float(__builtin_amdgcn_readlane(__float_as_int(v), lane));
}
__device__ __forceinline__ float fast_sigmoid(float x) {
    x = fminf(fmaxf(x, -30.f), 30.f);
    return 1.f / (1.f + __expf(-x));
}
__device__ __forceinline__ float fast_tanh(float x) {
    x = fminf(fmaxf(x, -15.f), 15.f);
    float e = __expf(2.f * x);
    return (e - 1.f) / (e + 1.f);
}

// ---------------------------------------------------------------------------
// Pass 1: dense fp32 adjacency -> CSR (per (e, target n): list of sources m).
// ---------------------------------------------------------------------------
__global__ __launch_bounds__(256) void build_csr(const float* __restrict__ edges,
                                                 int* __restrict__ deg,
                                                 int* __restrict__ csr) {
    int t = blockIdx.x * 256 + threadIdx.x;
    int idx4 = t * 4;
    float4 v = *reinterpret_cast<const float4*>(edges + idx4);
    if (v.x == 0.f && v.y == 0.f && v.z == 0.f && v.w == 0.f) return;
    int e   = idx4 / NNi;
    int rem = idx4 - e * NNi;
    int m   = rem / N;
    int nb  = rem - m * N;
    float w[4] = {v.x, v.y, v.z, v.w};
    int base = e * N + nb;
    #pragma unroll
    for (int j = 0; j < 4; ++j) {
        if (w[j] != 0.f) {
            int slot = base + j;
            int pos = atomicAdd(&deg[slot], 1);
            if (pos < CAP) csr[slot * CAP + pos] = m;
        }
    }
}

// ---------------------------------------------------------------------------
// Fused cooperative kernel: init_h + 3 layers x 5 iterations + epilogue.
// One wave per node; lane = (g,s). acc0 = act[g][s], acc1 = act[g+2][s].
// LDS 61.7 KB; __launch_bounds__(512,4) pins VGPR<=128 -> 2 blocks/CU bucket
// -> cooperative capacity 512 blocks >= 384 launched.
// ---------------------------------------------------------------------------
struct Params {
    const float *x, *fcw, *fcb;
    const float *wz, *wr, *wh, *uz, *ur, *uh, *bz, *br;
    const float *ow, *ob;
    const int   *deg, *csr;
    float *h0, *h1, *out;
    int   *flag;
};

__global__ __launch_bounds__(TPB, 4) void fused_ggnn(Params p) {
    cg::grid_group grid = cg::this_grid();
    __shared__ __align__(16) float sW[3 * 4096];   // [z|r|h][e][k][s]
    __shared__ __align__(16) float sU[3 * 1024];   // [z|r|h][k][s]
    __shared__ float sB[64];                       // [bz|br][s]

    const int tid  = threadIdx.x;
    const int b    = blockIdx.x;
    const int wid  = tid >> 6;
    const int lane = tid & 63;
    const int s    = lane & 31;
    const int g    = lane >> 5;
    const int n    = b * 8 + wid;

    // ---- init: h0 = x @ fc_w + fc_b ; zero dummy rows of both buffers
    if (tid < 256) {
        int n0 = b * 8 + (tid >> 5);
        int s0 = tid & 31;
        float acc = p.fcb[s0];
        #pragma unroll 8
        for (int k = 0; k < FIN; ++k)
            acc = fmaf(p.x[n0 * FIN + k], p.fcw[k * S + s0], acc);
        p.h0[n0 * S + s0] = acc;
    } else if (b == 0) {
        if (tid < 288)      p.h0[DUMMY * S + (tid - 256)] = 0.f;
        else if (tid < 320) p.h1[DUMMY * S + (tid - 288)] = 0.f;
    }

    // ---- iteration-invariant CSR state
    const int slot1 = g * N + n;
    const int slot2 = (g + 2) * N + n;
    const int d1 = min(p.deg[slot1], CAP);
    const int d2 = min(p.deg[slot2], CAP);
    const int* __restrict__ l1 = p.csr + slot1 * CAP;
    const int* __restrict__ l2 = p.csr + slot2 * CAP;
    const int dm = max(d1, d2);

    const float* hp = p.h0;
    float*       hn = p.h1;
    float hlast = 0.f;                             // final h[n][s], kept in-register

    for (int l = 0; l < 3; ++l) {
        __syncthreads();                           // guard LDS reuse across layers
        {
            float4* dw = (float4*)sW;
            const float4* gz = (const float4*)(p.wz + l * 4096);
            const float4* gr = (const float4*)(p.wr + l * 4096);
            const float4* gh = (const float4*)(p.wh + l * 4096);
            for (int i = tid; i < 1024; i += TPB) {
                dw[i] = gz[i]; dw[1024 + i] = gr[i]; dw[2048 + i] = gh[i];
            }
            float4* du = (float4*)sU;
            const float4* guz = (const float4*)(p.uz + l * 1024);
            const float4* gur = (const float4*)(p.ur + l * 1024);
            const float4* guh = (const float4*)(p.uh + l * 1024);
            if (tid < 256) {
                du[tid] = guz[tid]; du[256 + tid] = gur[tid]; du[512 + tid] = guh[tid];
            }
            if (tid < 64) sB[tid] = (tid < 32) ? p.bz[l * 32 + tid]
                                               : p.br[l * 32 + (tid - 32)];
        }
        __syncthreads();

        for (int it = 0; it < 5; ++it) {
            grid.sync();   // hp fully written device-wide (init or prev iteration)

            // ---- phase A: sparse gather, 4-wide index chunks, dummy-padded
            float acc0 = 0.f, acc1 = 0.f;
            for (int c = 0; c < dm; c += 4) {
                int4 ia = *reinterpret_cast<const int4*>(l1 + c);
                int4 ib = *reinterpret_cast<const int4*>(l2 + c);
                int r0 = (c + 0 < d1) ? ia.x : DUMMY;
                int r1 = (c + 1 < d1) ? ia.y : DUMMY;
                int r2 = (c + 2 < d1) ? ia.z : DUMMY;
                int r3 = (c + 3 < d1) ? ia.w : DUMMY;
                int q0 = (c + 0 < d2) ? ib.x : DUMMY;
                int q1 = (c + 1 < d2) ? ib.y : DUMMY;
                int q2 = (c + 2 < d2) ? ib.z : DUMMY;
                int q3 = (c + 3 < d2) ? ib.w : DUMMY;
                float v0 = hp[r0 * S + s], v1 = hp[r1 * S + s];
                float v2 = hp[r2 * S + s], v3 = hp[r3 * S + s];
                float u0 = hp[q0 * S + s], u1 = hp[q1 * S + s];
                float u2 = hp[q2 * S + s], u3 = hp[q3 * S + s];
                acc0 += (v0 + v1) + (v2 + v3);
                acc1 += (u0 + u1) + (u2 + u3);
            }
            const float hval = hp[n * S + s];

            // ---- phases B+C: z|r gate (split across halves) + hh
            const float* __restrict__ W1 = g ? (sW + 4096) : sW;
            const float* __restrict__ U1 = g ? (sU + 1024) : sU;
            const float* __restrict__ Wh = sW + 8192;
            float accA = sB[g * 32 + s];
            float accB = 0.f;
            float hA = 0.f, hB = 0.f;
            #pragma unroll
            for (int e = 0; e < E; ++e) {
                const float src = (e < 2) ? acc0 : acc1;
                const float* w1c = W1 + e * 1024 + s;
                const float* whc = Wh + e * 1024 + s;
                #pragma unroll
                for (int k = 0; k < 32; k += 2) {
                    float a0 = rl(src, (e & 1) * 32 + k);
                    float a1 = rl(src, (e & 1) * 32 + k + 1);
                    accA = fmaf(a0, w1c[(k)     * 32], accA);
                    accB = fmaf(a1, w1c[(k + 1) * 32], accB);
                    hA   = fmaf(a0, whc[(k)     * 32], hA);
                    hB   = fmaf(a1, whc[(k + 1) * 32], hB);
                }
            }
            #pragma unroll
            for (int k = 0; k < 32; k += 2) {
                accA = fmaf(rl(hval, k),     U1[(k)     * 32 + s], accA);
                accB = fmaf(rl(hval, k + 1), U1[(k + 1) * 32 + s], accB);
            }
            const float zr  = fast_sigmoid(accA + accB);   // z (g=0) | r (g=1)
            const float r_s = __shfl(zr, 32 + s, 64);
            const float z_s = __shfl(zr, s, 64);
            const float rh  = r_s * hval;
            const float* __restrict__ Uh = sU + 2048;
            #pragma unroll
            for (int k = 0; k < 32; k += 2) {
                hA = fmaf(rl(rh, k),     Uh[(k)     * 32 + s], hA);
                hB = fmaf(rl(rh, k + 1), Uh[(k + 1) * 32 + s], hB);
            }
            const float hh   = fast_tanh(hA + hB);
            const float hnew = fmaf(z_s, hval - hh, hh);   // z*h + (1-z)*hh
            if (g == 0) hn[n * S + s] = hnew;
            hlast = hnew;

            float* t = (float*)hp; hp = hn; hn = t;        // swap
        }
    }

    // ---- epilogue fully in-register: wave 5 of block 0 owns node 5
    if (b == 0 && wid == 5) {
        float y[5];
        #pragma unroll
        for (int j = 0; j < 5; ++j) y[j] = hlast * p.ow[s * 5 + j];
        #pragma unroll
        for (int off = 1; off < 32; off <<= 1) {
            #pragma unroll
            for (int j = 0; j < 5; ++j) y[j] += __shfl_xor(y[j], off, 64);
        }
        #pragma unroll
        for (int j = 0; j < 5; ++j) y[j] += p.ob[j];
        float m = -1e30f;
        #pragma unroll
        for (int j = 0; j < 5; ++j) m = fmaxf(m, y[j]);
        float ssum = 0.f;
        #pragma unroll
        for (int j = 0; j < 5; ++j) ssum += __expf(y[j] - m);
        float lse = m + __logf(ssum);
        #pragma unroll
        for (int j = 0; j < 5; ++j) if (lane == j) p.out[j] = y[j] - lse;
    }
    if (b == 0 && tid == 0) *p.flag = 1;           // fused path completed
}

// ---------------------------------------------------------------------------
// Fallback chain (round-3 known-good kernels + early-exit flag). Runs only if
// the cooperative launch was rejected.
// ---------------------------------------------------------------------------
__global__ __launch_bounds__(256) void init_h_fb(const int* __restrict__ flag,
                                                 const float* __restrict__ x,
                                                 const float* __restrict__ fcw,
                                                 const float* __restrict__ fcb,
                                                 float* __restrict__ h0) {
    if (*flag == 1) return;
    int t = blockIdx.x * 256 + threadIdx.x;
    int s = t & 31;
    int n = t >> 5;
    float acc = fcb[s];
    #pragma unroll 8
    for (int k = 0; k < FIN; ++k)
        acc = fmaf(x[n * FIN + k], fcw[k * S + s], acc);
    h0[n * S + s] = acc;
}

__global__ __launch_bounds__(512) void ggnn_iter_fb(const int* __restrict__ flag,
    const float* __restrict__ hprev, float* __restrict__ hnext,
    const int* __restrict__ deg, const int* __restrict__ csr,
    const float* __restrict__ wz, const float* __restrict__ wr, const float* __restrict__ wh,
    const float* __restrict__ uz, const float* __restrict__ ur, const float* __restrict__ uh,
    const float* __restrict__ bz, const float* __restrict__ br) {
    if (*flag == 1) return;
    __shared__ __align__(16) float sWz[4096];
    __shared__ __align__(16) float sWr[4096];
    __shared__ __align__(16) float sWh[4096];
    __shared__ __align__(16) float sUz[1024], sUr[1024], sUh[1024];

    int tid = threadIdx.x;
    {
        float4*       dz = (float4*)sWz; const float4* gz = (const float4*)wz;
        float4*       dr = (float4*)sWr; const float4* gr = (const float4*)wr;
        float4*       dh = (float4*)sWh; const float4* gh = (const float4*)wh;
        for (int i = tid; i < 1024; i += 512) { dz[i] = gz[i]; dr[i] = gr[i]; dh[i] = gh[i]; }
        float4*       duz = (float4*)sUz; const float4* guz = (const float4*)uz;
        float4*       dur = (float4*)sUr; const float4* gur = (const float4*)ur;
        float4*       duh = (float4*)sUh; const float4* guh = (const float4*)uh;
        if (tid < 256) { duz[tid] = guz[tid]; dur[tid] = gur[tid]; duh[tid] = guh[tid]; }
    }
    __syncthreads();

    const int wid  = tid >> 6;
    const int lane = tid & 63;
    const int s    = lane & 31;
    const int g    = lane >> 5;
    const int n    = blockIdx.x * 8 + wid;

    const int d1 = min(deg[g * N + n], CAP);
    const int d2 = min(deg[(g + 2) * N + n], CAP);
    const int* __restrict__ l1 = csr + (g * N + n) * CAP;
    const int* __restrict__ l2 = csr + ((g + 2) * N + n) * CAP;
    float acc0 = 0.f, acc1 = 0.f;
    const int dmax = max(d1, d2);
    for (int i = 0; i < dmax; ++i) {
        if (i < d1) acc0 += hprev[l1[i] * S + s];
        if (i < d2) acc1 += hprev[l2[i] * S + s];
    }
    const float hval = hprev[n * S + s];

    const float* __restrict__ W1 = g ? sWr : sWz;
    const float* __restrict__ U1 = g ? sUr : sUz;
    float accA = g ? br[s] : bz[s];
    float accB = 0.f;
    float hA = 0.f, hB = 0.f;
    #pragma unroll
    for (int e = 0; e < E; ++e) {
        const float src = (e < 2) ? acc0 : acc1;
        const float* w1c = W1 + e * 1024 + s;
        const float* whc = sWh + e * 1024 + s;
        #pragma unroll
        for (int k = 0; k < 32; k += 2) {
            float a0 = rl(src, (e & 1) * 32 + k);
            float a1 = rl(src, (e & 1) * 32 + k + 1);
            accA = fmaf(a0, w1c[(k)     * 32], accA);
            accB = fmaf(a1, w1c[(k + 1) * 32], accB);
            hA   = fmaf(a0, whc[(k)     * 32], hA);
            hB   = fmaf(a1, whc[(k + 1) * 32], hB);
        }
    }
    #pragma unroll
    for (int k = 0; k < 32; k += 2) {
        accA = fmaf(rl(hval, k),     U1[(k)     * 32 + s], accA);
        accB = fmaf(rl(hval, k + 1), U1[(k + 1) * 32 + s], accB);
    }
    const float zr  = fast_sigmoid(accA + accB);
    const float r_s = __shfl(zr, 32 + s, 64);
    const float z_s = __shfl(zr, s, 64);
    const float rh  = r_s * hval;
    #pragma unroll
    for (int k = 0; k < 32; k += 2) {
        hA = fmaf(rl(rh, k),     sUh[(k)     * 32 + s], hA);
        hB = fmaf(rl(rh, k + 1), sUh[(k + 1) * 32 + s], hB);
    }
    const float hh = fast_tanh(hA + hB);
    const float hnew = fmaf(z_s, hval - hh, hh);
    if (g == 0) hnext[n * S + s] = hnew;
}

__global__ void epilogue_fb(const int* __restrict__ flag,
                            const float* __restrict__ h,
                            const float* __restrict__ ow, const float* __restrict__ ob,
                            float* __restrict__ out) {
    if (*flag == 1) return;
    int lane = threadIdx.x;
    float y = 0.f;
    if (lane < 5) {
        y = ob[lane];
        for (int k = 0; k < 32; ++k)
            y = fmaf(h[5 * S + k], ow[k * 5 + lane], y);
    }
    float m = -1e30f;
    #pragma unroll
    for (int j = 0; j < 5; ++j) m = fmaxf(m, __shfl(y, j, 64));
    float ssum = 0.f;
    #pragma unroll
    for (int j = 0; j < 5; ++j) ssum += __expf(__shfl(y, j, 64) - m);
    float lse = m + __logf(ssum);
    if (lane < 5) out[lane] = y - lse;
}

extern "C" void kernel_launch(void* const* d_in, const int* in_sizes, int n_in,
                              void* d_out, int out_size, void* d_ws, size_t ws_size,
                              hipStream_t stream) {
    const float* x     = (const float*)d_in[0];
    const float* edges = (const float*)d_in[2];
    const float* fcw   = (const float*)d_in[3];
    const float* fcb   = (const float*)d_in[4];
    const float* wz    = (const float*)d_in[5];
    const float* wr    = (const float*)d_in[6];
    const float* wh    = (const float*)d_in[7];
    const float* uz    = (const float*)d_in[8];
    const float* ur    = (const float*)d_in[9];
    const float* uh    = (const float*)d_in[10];
    const float* bz    = (const float*)d_in[11];
    const float* br    = (const float*)d_in[12];
    const float* ow    = (const float*)d_in[13];
    const float* ob    = (const float*)d_in[14];

    char* ws = (char*)d_ws;
    float* h0   = (float*)(ws);                  // 3073 rows * 32 * 4 = 393,344 B
    float* h1   = (float*)(ws + 393600);
    int*   deg  = (int*)(ws + 787200);           //  49,152 B
    int*   csr  = (int*)(ws + 836352);           // 3,145,728 B
    int*   flag = (int*)(ws + 3982080);

    hipMemsetAsync(deg, 0, E * N * sizeof(int), stream);
    build_csr<<<36864, 256, 0, stream>>>(edges, deg, csr);

    Params p;
    p.x = x; p.fcw = fcw; p.fcb = fcb;
    p.wz = wz; p.wr = wr; p.wh = wh;
    p.uz = uz; p.ur = ur; p.uh = uh;
    p.bz = bz; p.br = br; p.ow = ow; p.ob = ob;
    p.deg = deg; p.csr = csr;
    p.h0 = h0; p.h1 = h1; p.out = (float*)d_out; p.flag = flag;

    void* args[] = { &p };
    (void)hipLaunchCooperativeKernel((const void*)fused_ggnn, dim3(BLK), dim3(TPB),
                                     args, 0, stream);

    // Fallback chain: no-ops (flag==1) when the cooperative kernel ran.
    init_h_fb<<<384, 256, 0, stream>>>(flag, x, fcw, fcb, h0);
    float* ha = h0;
    float* hb = h1;
    for (int l = 0; l < 3; ++l) {
        for (int it = 0; it < 5; ++it) {
            ggnn_iter_fb<<<384, 512, 0, stream>>>(flag, ha, hb, deg, csr,
                wz + l * 4096, wr + l * 4096, wh + l * 4096,
                uz + l * 1024, ur + l * 1024, uh + l * 1024,
                bz + l * 32, br + l * 32);
            float* t = ha; ha = hb; hb = t;
        }
    }
    epilogue_fb<<<1, 64, 0, stream>>>(flag, ha, ow, ob, (float*)d_out);
}

// Round 7
// 623.064 us; speedup vs baseline: 1.6618x; 1.6618x over previous
//
#include <hip/hip_runtime.h>

constexpr int N     = 3072;
constexpr int S     = 32;
constexpr int E     = 4;
constexpr int FIN   = 64;
constexpr int CAP   = 64;     // max sources per (e,n); Binomial(3072,0.005) mean 15.4, P(>=64)~1e-19
constexpr int NNi   = N * N;  // 9,437,184
constexpr int DUMMY = N;      // extra all-zero h row for gather padding
constexpr int BLK   = 384;    // coop grid; LDS-limited 2 blocks/CU * 256 CU = 512 >= 384
constexpr int TPB   = 512;    // 8 waves = 8 nodes per block; 384*8 = 3072

__device__ __forceinline__ float rl(float v, int lane) {   // wave-uniform broadcast via VALU
    return __int_as_float(__builtin_amdgcn_readlane(__float_as_int(v), lane));
}
__device__ __forceinline__ float fast_sigmoid(float x) {
    x = fminf(fmaxf(x, -30.f), 30.f);
    return 1.f / (1.f + __expf(-x));
}
__device__ __forceinline__ float fast_tanh(float x) {
    x = fminf(fmaxf(x, -15.f), 15.f);
    float e = __expf(2.f * x);
    return (e - 1.f) / (e + 1.f);
}

// Cache-bypassing accessors: relaxed AGENT-scope atomics are coherent at the
// memory-side Infinity Cache (above the non-coherent per-XCD L2s).
__device__ __forceinline__ float ld_dev(const float* p) {
    return __hip_atomic_load((float*)p, __ATOMIC_RELAXED, __HIP_MEMORY_SCOPE_AGENT);
}
__device__ __forceinline__ void st_dev(float* p, float v) {
    __hip_atomic_store(p, v, __ATOMIC_RELAXED, __HIP_MEMORY_SCOPE_AGENT);
}

// Reset-free monotone grid barrier; bounded spin (wedge -> limp home, fallback
// chain recomputes). Ordering: __syncthreads() drains vmcnt(0), and all
// cross-block data uses bypass ops, so relaxed counter ops suffice.
__device__ __forceinline__ bool gbar(int* cnt, int target) {
    __shared__ int ok;
    __syncthreads();
    if (threadIdx.x == 0) {
        __hip_atomic_fetch_add(cnt, 1, __ATOMIC_RELAXED, __HIP_MEMORY_SCOPE_AGENT);
        int spins = 0;
        while (__hip_atomic_load(cnt, __ATOMIC_RELAXED, __HIP_MEMORY_SCOPE_AGENT) < target) {
            __builtin_amdgcn_s_sleep(8);
            if (++spins > 100000) break;           // ~20 ms: declare wedged
        }
        ok = (spins <= 100000) ? 1 : 0;
    }
    __syncthreads();
    return ok != 0;
}

// ---------------------------------------------------------------------------
// Pass 1 (separate dispatch; inter-dispatch flush makes results coherent):
// dense fp32 adjacency -> CSR (per (e, target n): list of sources m).
// ---------------------------------------------------------------------------
__global__ __launch_bounds__(256) void build_csr(const float* __restrict__ edges,
                                                 int* __restrict__ deg,
                                                 int* __restrict__ csr) {
    int t = blockIdx.x * 256 + threadIdx.x;
    int idx4 = t * 4;
    float4 v = *reinterpret_cast<const float4*>(edges + idx4);
    if (v.x == 0.f && v.y == 0.f && v.z == 0.f && v.w == 0.f) return;
    int e   = idx4 / NNi;
    int rem = idx4 - e * NNi;
    int m   = rem / N;
    int nb  = rem - m * N;
    float w[4] = {v.x, v.y, v.z, v.w};
    int base = e * N + nb;
    #pragma unroll
    for (int j = 0; j < 4; ++j) {
        if (w[j] != 0.f) {
            int slot = base + j;
            int pos = atomicAdd(&deg[slot], 1);
            if (pos < CAP) csr[slot * CAP + pos] = m;
        }
    }
}

struct Params {
    const float *x, *fcw, *fcb;
    const float *wz, *wr, *wh, *uz, *ur, *uh, *bz, *br;
    const float *ow, *ob;
    const int   *deg, *csr;
    int   *cnt;
    float *h0, *h1, *out;
    int   *flag;
};

// ---------------------------------------------------------------------------
// Fused cooperative kernel: init_h + 3 layers x 5 iterations + epilogue.
// Identical compute to the round-5 passing kernel; only the sync layer differs
// (custom gbar + bypassed h traffic instead of cg::grid.sync).
// LDS 61.7 KB -> 2 blocks/CU; __launch_bounds__(512,4) caps VGPR at 128.
// ---------------------------------------------------------------------------
__global__ __launch_bounds__(TPB, 4) void fused_ggnn(Params p) {
    __shared__ __align__(16) float sW[3 * 4096];   // [z|r|h][e][k][s]
    __shared__ __align__(16) float sU[3 * 1024];   // [z|r|h][k][s]
    __shared__ float sB[64];                       // [bz|br][s]

    const int tid  = threadIdx.x;
    const int b    = blockIdx.x;
    const int wid  = tid >> 6;
    const int lane = tid & 63;
    const int s    = lane & 31;
    const int g    = lane >> 5;
    const int n    = b * 8 + wid;

    // ---- init: h0 = x @ fc_w + fc_b (bypass stores); zero dummy rows
    if (tid < 256) {
        int n0 = b * 8 + (tid >> 5);
        int s0 = tid & 31;
        float acc = p.fcb[s0];
        #pragma unroll 8
        for (int k = 0; k < FIN; ++k)
            acc = fmaf(p.x[n0 * FIN + k], p.fcw[k * S + s0], acc);
        st_dev(&p.h0[n0 * S + s0], acc);
    } else if (b == 0) {
        if (tid < 288)      st_dev(&p.h0[DUMMY * S + (tid - 256)], 0.f);
        else if (tid < 320) st_dev(&p.h1[DUMMY * S + (tid - 288)], 0.f);
    }

    // ---- iteration-invariant CSR state (prev-dispatch data: cached reads OK)
    const int slot1 = g * N + n;
    const int slot2 = (g + 2) * N + n;
    const int d1 = min(p.deg[slot1], CAP);
    const int d2 = min(p.deg[slot2], CAP);
    const int* __restrict__ l1 = p.csr + slot1 * CAP;
    const int* __restrict__ l2 = p.csr + slot2 * CAP;
    const int dm = max(d1, d2);

    const float* hp = p.h0;
    float*       hn = p.h1;
    float hlast = 0.f;
    bool  alive = true;
    int   phase = 1;

    alive = gbar(p.cnt, BLK * phase) && alive; phase++;   // h0 device-visible

    for (int l = 0; l < 3; ++l) {
        __syncthreads();                           // guard LDS reuse across layers
        {
            float4* dw = (float4*)sW;
            const float4* gz = (const float4*)(p.wz + l * 4096);
            const float4* gr = (const float4*)(p.wr + l * 4096);
            const float4* gh = (const float4*)(p.wh + l * 4096);
            for (int i = tid; i < 1024; i += TPB) {
                dw[i] = gz[i]; dw[1024 + i] = gr[i]; dw[2048 + i] = gh[i];
            }
            float4* du = (float4*)sU;
            const float4* guz = (const float4*)(p.uz + l * 1024);
            const float4* gur = (const float4*)(p.ur + l * 1024);
            const float4* guh = (const float4*)(p.uh + l * 1024);
            if (tid < 256) {
                du[tid] = guz[tid]; du[256 + tid] = gur[tid]; du[512 + tid] = guh[tid];
            }
            if (tid < 64) sB[tid] = (tid < 32) ? p.bz[l * 32 + tid]
                                               : p.br[l * 32 + (tid - 32)];
        }
        __syncthreads();

        for (int it = 0; it < 5; ++it) {
            // ---- phase A: sparse gather (bypass loads), 4-wide, dummy-padded
            float acc0 = 0.f, acc1 = 0.f;
            for (int c = 0; c < dm; c += 4) {
                int4 ia = *reinterpret_cast<const int4*>(l1 + c);
                int4 ib = *reinterpret_cast<const int4*>(l2 + c);
                int r0 = (c + 0 < d1) ? ia.x : DUMMY;
                int r1 = (c + 1 < d1) ? ia.y : DUMMY;
                int r2 = (c + 2 < d1) ? ia.z : DUMMY;
                int r3 = (c + 3 < d1) ? ia.w : DUMMY;
                int q0 = (c + 0 < d2) ? ib.x : DUMMY;
                int q1 = (c + 1 < d2) ? ib.y : DUMMY;
                int q2 = (c + 2 < d2) ? ib.z : DUMMY;
                int q3 = (c + 3 < d2) ? ib.w : DUMMY;
                float v0 = ld_dev(hp + r0 * S + s), v1 = ld_dev(hp + r1 * S + s);
                float v2 = ld_dev(hp + r2 * S + s), v3 = ld_dev(hp + r3 * S + s);
                float u0 = ld_dev(hp + q0 * S + s), u1 = ld_dev(hp + q1 * S + s);
                float u2 = ld_dev(hp + q2 * S + s), u3 = ld_dev(hp + q3 * S + s);
                acc0 += (v0 + v1) + (v2 + v3);
                acc1 += (u0 + u1) + (u2 + u3);
            }
            const float hval = ld_dev(hp + n * S + s);

            // ---- phases B+C: z|r gate (split across wave halves) + hh
            const float* __restrict__ W1 = g ? (sW + 4096) : sW;
            const float* __restrict__ U1 = g ? (sU + 1024) : sU;
            const float* __restrict__ Wh = sW + 8192;
            float accA = sB[g * 32 + s];
            float accB = 0.f;
            float hA = 0.f, hB = 0.f;
            #pragma unroll
            for (int e = 0; e < E; ++e) {
                const float src = (e < 2) ? acc0 : acc1;
                const float* w1c = W1 + e * 1024 + s;
                const float* whc = Wh + e * 1024 + s;
                #pragma unroll
                for (int k = 0; k < 32; k += 2) {
                    float a0 = rl(src, (e & 1) * 32 + k);
                    float a1 = rl(src, (e & 1) * 32 + k + 1);
                    accA = fmaf(a0, w1c[(k)     * 32], accA);
                    accB = fmaf(a1, w1c[(k + 1) * 32], accB);
                    hA   = fmaf(a0, whc[(k)     * 32], hA);
                    hB   = fmaf(a1, whc[(k + 1) * 32], hB);
                }
            }
            #pragma unroll
            for (int k = 0; k < 32; k += 2) {
                accA = fmaf(rl(hval, k),     U1[(k)     * 32 + s], accA);
                accB = fmaf(rl(hval, k + 1), U1[(k + 1) * 32 + s], accB);
            }
            const float zr  = fast_sigmoid(accA + accB);   // z (g=0) | r (g=1)
            const float r_s = __shfl(zr, 32 + s, 64);
            const float z_s = __shfl(zr, s, 64);
            const float rh  = r_s * hval;
            const float* __restrict__ Uh = sU + 2048;
            #pragma unroll
            for (int k = 0; k < 32; k += 2) {
                hA = fmaf(rl(rh, k),     Uh[(k)     * 32 + s], hA);
                hB = fmaf(rl(rh, k + 1), Uh[(k + 1) * 32 + s], hB);
            }
            const float hh   = fast_tanh(hA + hB);
            const float hnew = fmaf(z_s, hval - hh, hh);   // z*h + (1-z)*hh
            if (g == 0) st_dev(&hn[n * S + s], hnew);
            hlast = hnew;

            float* t = (float*)hp; hp = hn; hn = t;        // swap

            if (l != 2 || it != 4) {                       // no barrier after last iter
                alive = gbar(p.cnt, BLK * phase) && alive; phase++;
            }
        }
    }

    // ---- epilogue in-register: wave 5 of block 0 owns node 5 (h in hlast)
    if (b == 0 && wid == 5) {
        float y[5];
        #pragma unroll
        for (int j = 0; j < 5; ++j) y[j] = hlast * p.ow[s * 5 + j];
        #pragma unroll
        for (int off = 1; off < 32; off <<= 1) {
            #pragma unroll
            for (int j = 0; j < 5; ++j) y[j] += __shfl_xor(y[j], off, 64);
        }
        #pragma unroll
        for (int j = 0; j < 5; ++j) y[j] += p.ob[j];
        float m = -1e30f;
        #pragma unroll
        for (int j = 0; j < 5; ++j) m = fmaxf(m, y[j]);
        float ssum = 0.f;
        #pragma unroll
        for (int j = 0; j < 5; ++j) ssum += __expf(y[j] - m);
        float lse = m + __logf(ssum);
        #pragma unroll
        for (int j = 0; j < 5; ++j) if (lane == j) p.out[j] = y[j] - lse;
    }
    if (b == 0 && tid == 0 && alive) *p.flag = 1;  // fused path completed cleanly
}

// ---------------------------------------------------------------------------
// Fallback chain (round-3/5 known-good kernels + early-exit flag). Runs only
// if the cooperative launch was rejected or a barrier timed out.
// ---------------------------------------------------------------------------
__global__ __launch_bounds__(256) void init_h_fb(const int* __restrict__ flag,
                                                 const float* __restrict__ x,
                                                 const float* __restrict__ fcw,
                                                 const float* __restrict__ fcb,
                                                 float* __restrict__ h0) {
    if (*flag == 1) return;
    int t = blockIdx.x * 256 + threadIdx.x;
    int s = t & 31;
    int n = t >> 5;
    float acc = fcb[s];
    #pragma unroll 8
    for (int k = 0; k < FIN; ++k)
        acc = fmaf(x[n * FIN + k], fcw[k * S + s], acc);
    h0[n * S + s] = acc;
}

__global__ __launch_bounds__(512) void ggnn_iter_fb(const int* __restrict__ flag,
    const float* __restrict__ hprev, float* __restrict__ hnext,
    const int* __restrict__ deg, const int* __restrict__ csr,
    const float* __restrict__ wz, const float* __restrict__ wr, const float* __restrict__ wh,
    const float* __restrict__ uz, const float* __restrict__ ur, const float* __restrict__ uh,
    const float* __restrict__ bz, const float* __restrict__ br) {
    if (*flag == 1) return;
    __shared__ __align__(16) float sWz[4096];
    __shared__ __align__(16) float sWr[4096];
    __shared__ __align__(16) float sWh[4096];
    __shared__ __align__(16) float sUz[1024], sUr[1024], sUh[1024];

    int tid = threadIdx.x;
    {
        float4*       dz = (float4*)sWz; const float4* gz = (const float4*)wz;
        float4*       dr = (float4*)sWr; const float4* gr = (const float4*)wr;
        float4*       dh = (float4*)sWh; const float4* gh = (const float4*)wh;
        for (int i = tid; i < 1024; i += 512) { dz[i] = gz[i]; dr[i] = gr[i]; dh[i] = gh[i]; }
        float4*       duz = (float4*)sUz; const float4* guz = (const float4*)uz;
        float4*       dur = (float4*)sUr; const float4* gur = (const float4*)ur;
        float4*       duh = (float4*)sUh; const float4* guh = (const float4*)uh;
        if (tid < 256) { duz[tid] = guz[tid]; dur[tid] = gur[tid]; duh[tid] = guh[tid]; }
    }
    __syncthreads();

    const int wid  = tid >> 6;
    const int lane = tid & 63;
    const int s    = lane & 31;
    const int g    = lane >> 5;
    const int n    = blockIdx.x * 8 + wid;

    const int d1 = min(deg[g * N + n], CAP);
    const int d2 = min(deg[(g + 2) * N + n], CAP);
    const int* __restrict__ l1 = csr + (g * N + n) * CAP;
    const int* __restrict__ l2 = csr + ((g + 2) * N + n) * CAP;
    float acc0 = 0.f, acc1 = 0.f;
    const int dmax = max(d1, d2);
    for (int i = 0; i < dmax; ++i) {
        if (i < d1) acc0 += hprev[l1[i] * S + s];
        if (i < d2) acc1 += hprev[l2[i] * S + s];
    }
    const float hval = hprev[n * S + s];

    const float* __restrict__ W1 = g ? sWr : sWz;
    const float* __restrict__ U1 = g ? sUr : sUz;
    float accA = g ? br[s] : bz[s];
    float accB = 0.f;
    float hA = 0.f, hB = 0.f;
    #pragma unroll
    for (int e = 0; e < E; ++e) {
        const float src = (e < 2) ? acc0 : acc1;
        const float* w1c = W1 + e * 1024 + s;
        const float* whc = sWh + e * 1024 + s;
        #pragma unroll
        for (int k = 0; k < 32; k += 2) {
            float a0 = rl(src, (e & 1) * 32 + k);
            float a1 = rl(src, (e & 1) * 32 + k + 1);
            accA = fmaf(a0, w1c[(k)     * 32], accA);
            accB = fmaf(a1, w1c[(k + 1) * 32], accB);
            hA   = fmaf(a0, whc[(k)     * 32], hA);
            hB   = fmaf(a1, whc[(k + 1) * 32], hB);
        }
    }
    #pragma unroll
    for (int k = 0; k < 32; k += 2) {
        accA = fmaf(rl(hval, k),     U1[(k)     * 32 + s], accA);
        accB = fmaf(rl(hval, k + 1), U1[(k + 1) * 32 + s], accB);
    }
    const float zr  = fast_sigmoid(accA + accB);
    const float r_s = __shfl(zr, 32 + s, 64);
    const float z_s = __shfl(zr, s, 64);
    const float rh  = r_s * hval;
    #pragma unroll
    for (int k = 0; k < 32; k += 2) {
        hA = fmaf(rl(rh, k),     sUh[(k)     * 32 + s], hA);
        hB = fmaf(rl(rh, k + 1), sUh[(k + 1) * 32 + s], hB);
    }
    const float hh = fast_tanh(hA + hB);
    const float hnew = fmaf(z_s, hval - hh, hh);
    if (g == 0) hnext[n * S + s] = hnew;
}

__global__ void epilogue_fb(const int* __restrict__ flag,
                            const float* __restrict__ h,
                            const float* __restrict__ ow, const float* __restrict__ ob,
                            float* __restrict__ out) {
    if (*flag == 1) return;
    int lane = threadIdx.x;
    float y = 0.f;
    if (lane < 5) {
        y = ob[lane];
        for (int k = 0; k < 32; ++k)
            y = fmaf(h[5 * S + k], ow[k * 5 + lane], y);
    }
    float m = -1e30f;
    #pragma unroll
    for (int j = 0; j < 5; ++j) m = fmaxf(m, __shfl(y, j, 64));
    float ssum = 0.f;
    #pragma unroll
    for (int j = 0; j < 5; ++j) ssum += __expf(__shfl(y, j, 64) - m);
    float lse = m + __logf(ssum);
    if (lane < 5) out[lane] = y - lse;
}

extern "C" void kernel_launch(void* const* d_in, const int* in_sizes, int n_in,
                              void* d_out, int out_size, void* d_ws, size_t ws_size,
                              hipStream_t stream) {
    const float* x     = (const float*)d_in[0];
    // d_in[1] = x_lengths (int32) — unused by the reference
    const float* edges = (const float*)d_in[2];
    const float* fcw   = (const float*)d_in[3];
    const float* fcb   = (const float*)d_in[4];
    const float* wz    = (const float*)d_in[5];
    const float* wr    = (const float*)d_in[6];
    const float* wh    = (const float*)d_in[7];
    const float* uz    = (const float*)d_in[8];
    const float* ur    = (const float*)d_in[9];
    const float* uh    = (const float*)d_in[10];
    const float* bz    = (const float*)d_in[11];
    const float* br    = (const float*)d_in[12];
    const float* ow    = (const float*)d_in[13];
    const float* ob    = (const float*)d_in[14];

    char* ws = (char*)d_ws;
    float* h0   = (float*)(ws);                  // 3073 rows * 32 * 4 = 393,344 B
    float* h1   = (float*)(ws + 393600);
    int*   deg  = (int*)(ws + 787200);           // 49,152 B
    int*   cnt  = (int*)(ws + 836352);           // 128 B barrier counter
    int*   csr  = (int*)(ws + 836480);           // 3,145,728 B
    int*   flag = (int*)(ws + 3982208);

    // zero deg + cnt in one contiguous memset (flag left poisoned: fallback
    // armed unless the fused kernel completes and writes 1)
    hipMemsetAsync(deg, 0, 49152 + 128, stream);
    build_csr<<<36864, 256, 0, stream>>>(edges, deg, csr);

    Params p;
    p.x = x; p.fcw = fcw; p.fcb = fcb;
    p.wz = wz; p.wr = wr; p.wh = wh;
    p.uz = uz; p.ur = ur; p.uh = uh;
    p.bz = bz; p.br = br; p.ow = ow; p.ob = ob;
    p.deg = deg; p.csr = csr; p.cnt = cnt;
    p.h0 = h0; p.h1 = h1; p.out = (float*)d_out; p.flag = flag;

    void* args[] = { &p };
    (void)hipLaunchCooperativeKernel((const void*)fused_ggnn, dim3(BLK), dim3(TPB),
                                     args, 0, stream);

    // Fallback chain: no-ops (flag==1) when the fused kernel completed.
    init_h_fb<<<384, 256, 0, stream>>>(flag, x, fcw, fcb, h0);
    float* ha = h0;
    float* hb = h1;
    for (int l = 0; l < 3; ++l) {
        for (int it = 0; it < 5; ++it) {
            ggnn_iter_fb<<<384, 512, 0, stream>>>(flag, ha, hb, deg, csr,
                wz + l * 4096, wr + l * 4096, wh + l * 4096,
                uz + l * 1024, ur + l * 1024, uh + l * 1024,
                bz + l * 32, br + l * 32);
            float* t = ha; ha = hb; hb = t;
        }
    }
    epilogue_fb<<<1, 64, 0, stream>>>(flag, ha, ow, ob, (float*)d_out);
}

// Round 8
// 464.137 us; speedup vs baseline: 2.2308x; 1.3424x over previous
//
#include <hip/hip_runtime.h>

constexpr int N     = 3072;
constexpr int S     = 32;
constexpr int E     = 4;
constexpr int FIN   = 64;
constexpr int CAP   = 64;     // max sources per (e,n); Binomial(3072,0.005) mean 15.4, P(>=64)~1e-19
constexpr int NNi   = N * N;  // 9,437,184
constexpr int DUMMY = N;      // extra all-zero h row for gather padding
constexpr int BLK   = 256;    // 1 block/CU -> perfectly balanced, coop capacity OK
constexpr int TPB   = 768;    // 12 waves = 12 nodes per block; 256*12 = 3072
constexpr int NPB   = 12;

__device__ __forceinline__ float rl(float v, int lane) {   // wave-uniform broadcast via VALU
    return __int_as_float(__builtin_amdgcn_readlane(__float_as_int(v), lane));
}
__device__ __forceinline__ float fast_sigmoid(float x) {
    x = fminf(fmaxf(x, -30.f), 30.f);
    return 1.f / (1.f + __expf(-x));
}
__device__ __forceinline__ float fast_tanh(float x) {
    x = fminf(fmaxf(x, -15.f), 15.f);
    float e = __expf(2.f * x);
    return (e - 1.f) / (e + 1.f);
}

// Cache-bypassing accessors: relaxed AGENT-scope atomics are coherent at the
// memory-side Infinity Cache (above the non-coherent per-XCD L2s).
__device__ __forceinline__ float ld_dev(const float* p) {
    return __hip_atomic_load((float*)p, __ATOMIC_RELAXED, __HIP_MEMORY_SCOPE_AGENT);
}
__device__ __forceinline__ void st_dev(float* p, float v) {
    __hip_atomic_store(p, v, __ATOMIC_RELAXED, __HIP_MEMORY_SCOPE_AGENT);
}

// Two-level monotone tree barrier (reset-free). bar layout (ints):
//   [gi*16]  : group counters, one 64B line per group (16 groups of 16 blocks)
//   [256]    : root counter (group-last arrivers only, 16 adds/phase)
//   [272]    : go epoch (root-last writes phase number)
// Contention per line: 16 serialized RMWs instead of 384 on one line.
__device__ __forceinline__ bool gbar(int* bar, int ph, int b) {
    __shared__ int ok;
    __syncthreads();          // compiler drains vmcnt(0) before s_barrier
    if (threadIdx.x == 0) {
        int* grp  = bar + (b >> 4) * 16;
        int* root = bar + 256;
        int* go   = bar + 272;
        int old = __hip_atomic_fetch_add(grp, 1, __ATOMIC_RELAXED, __HIP_MEMORY_SCOPE_AGENT);
        if (old + 1 == ph * 16) {          // last of this group for phase ph
            int old2 = __hip_atomic_fetch_add(root, 1, __ATOMIC_RELAXED, __HIP_MEMORY_SCOPE_AGENT);
            if (old2 + 1 == ph * 16)       // last group overall
                __hip_atomic_store(go, ph, __ATOMIC_RELAXED, __HIP_MEMORY_SCOPE_AGENT);
        }
        int spins = 0, okl = 1;
        while (__hip_atomic_load(go, __ATOMIC_RELAXED, __HIP_MEMORY_SCOPE_AGENT) < ph) {
            __builtin_amdgcn_s_sleep(2);
            if (++spins > 300000) { okl = 0; break; }   // wedge -> terminate, not hang
        }
        ok = okl;
    }
    __syncthreads();
    return ok != 0;
}

// ---------------------------------------------------------------------------
// Pass 1 (separate dispatch; inter-dispatch flush makes results coherent):
// dense fp32 adjacency -> CSR (per (e, target n): list of sources m).
// ---------------------------------------------------------------------------
__global__ __launch_bounds__(256) void build_csr(const float* __restrict__ edges,
                                                 int* __restrict__ deg,
                                                 int* __restrict__ csr) {
    int t = blockIdx.x * 256 + threadIdx.x;
    int idx4 = t * 4;
    float4 v = *reinterpret_cast<const float4*>(edges + idx4);
    if (v.x == 0.f && v.y == 0.f && v.z == 0.f && v.w == 0.f) return;
    int e   = idx4 / NNi;
    int rem = idx4 - e * NNi;
    int m   = rem / N;
    int nb  = rem - m * N;
    float w[4] = {v.x, v.y, v.z, v.w};
    int base = e * N + nb;
    #pragma unroll
    for (int j = 0; j < 4; ++j) {
        if (w[j] != 0.f) {
            int slot = base + j;
            int pos = atomicAdd(&deg[slot], 1);
            if (pos < CAP) csr[slot * CAP + pos] = m;
        }
    }
}

struct Params {
    const float *x, *fcw, *fcb;
    const float *wz, *wr, *wh, *uz, *ur, *uh, *bz, *br;
    const float *ow, *ob;
    const int   *deg, *csr;
    int   *bar;
    float *h0, *h1, *out;
};

// ---------------------------------------------------------------------------
// Fused cooperative kernel: init_h + 3 layers x 5 iterations + epilogue.
// One wave per node; lane = (g,s). acc0 = act[g][s], acc1 = act[g+2][s].
// LDS 61.7 KB -> 1 block/CU at TPB=768 (12 waves); grid 256 = CU count.
// ---------------------------------------------------------------------------
__global__ __launch_bounds__(TPB, 1) void fused_ggnn(Params p) {
    __shared__ __align__(16) float sW[3 * 4096];   // [z|r|h][e][k][s]
    __shared__ __align__(16) float sU[3 * 1024];   // [z|r|h][k][s]
    __shared__ float sB[64];                       // [bz|br][s]

    const int tid  = threadIdx.x;
    const int b    = blockIdx.x;
    const int wid  = tid >> 6;
    const int lane = tid & 63;
    const int s    = lane & 31;
    const int g    = lane >> 5;
    const int n    = b * NPB + wid;

    // ---- init: h0 = x @ fc_w + fc_b (bypass stores); zero dummy rows
    if (tid < 32 * NPB) {
        int n0 = b * NPB + (tid >> 5);
        int s0 = tid & 31;
        float acc = p.fcb[s0];
        #pragma unroll 8
        for (int k = 0; k < FIN; ++k)
            acc = fmaf(p.x[n0 * FIN + k], p.fcw[k * S + s0], acc);
        st_dev(&p.h0[n0 * S + s0], acc);
    } else if (b == 0) {
        if (tid < 416)      st_dev(&p.h0[DUMMY * S + (tid - 384)], 0.f);
        else if (tid < 448) st_dev(&p.h1[DUMMY * S + (tid - 416)], 0.f);
    }

    // ---- iteration-invariant CSR state (prev-dispatch data: cached reads OK)
    const int slot1 = g * N + n;
    const int slot2 = (g + 2) * N + n;
    const int d1 = min(p.deg[slot1], CAP);
    const int d2 = min(p.deg[slot2], CAP);
    const int* __restrict__ l1 = p.csr + slot1 * CAP;
    const int* __restrict__ l2 = p.csr + slot2 * CAP;
    const int dm = max(d1, d2);

    const float* hp = p.h0;
    float*       hn = p.h1;
    float hlast = 0.f;
    int   phase = 1;

    gbar(p.bar, phase, b); phase++;                // h0 device-visible

    for (int l = 0; l < 3; ++l) {
        __syncthreads();                           // guard LDS reuse across layers
        {
            float4* dw = (float4*)sW;
            const float4* gz = (const float4*)(p.wz + l * 4096);
            const float4* gr = (const float4*)(p.wr + l * 4096);
            const float4* gh = (const float4*)(p.wh + l * 4096);
            for (int i = tid; i < 1024; i += TPB) {
                dw[i] = gz[i]; dw[1024 + i] = gr[i]; dw[2048 + i] = gh[i];
            }
            float4* du = (float4*)sU;
            const float4* guz = (const float4*)(p.uz + l * 1024);
            const float4* gur = (const float4*)(p.ur + l * 1024);
            const float4* guh = (const float4*)(p.uh + l * 1024);
            if (tid < 256) {
                du[tid] = guz[tid]; du[256 + tid] = gur[tid]; du[512 + tid] = guh[tid];
            }
            if (tid < 64) sB[tid] = (tid < 32) ? p.bz[l * 32 + tid]
                                               : p.br[l * 32 + (tid - 32)];
        }
        __syncthreads();

        for (int it = 0; it < 5; ++it) {
            // ---- phase A: sparse gather (bypass loads), 4-wide, dummy-padded
            float acc0 = 0.f, acc1 = 0.f;
            for (int c = 0; c < dm; c += 4) {
                int4 ia = *reinterpret_cast<const int4*>(l1 + c);
                int4 ib = *reinterpret_cast<const int4*>(l2 + c);
                int r0 = (c + 0 < d1) ? ia.x : DUMMY;
                int r1 = (c + 1 < d1) ? ia.y : DUMMY;
                int r2 = (c + 2 < d1) ? ia.z : DUMMY;
                int r3 = (c + 3 < d1) ? ia.w : DUMMY;
                int q0 = (c + 0 < d2) ? ib.x : DUMMY;
                int q1 = (c + 1 < d2) ? ib.y : DUMMY;
                int q2 = (c + 2 < d2) ? ib.z : DUMMY;
                int q3 = (c + 3 < d2) ? ib.w : DUMMY;
                float v0 = ld_dev(hp + r0 * S + s), v1 = ld_dev(hp + r1 * S + s);
                float v2 = ld_dev(hp + r2 * S + s), v3 = ld_dev(hp + r3 * S + s);
                float u0 = ld_dev(hp + q0 * S + s), u1 = ld_dev(hp + q1 * S + s);
                float u2 = ld_dev(hp + q2 * S + s), u3 = ld_dev(hp + q3 * S + s);
                acc0 += (v0 + v1) + (v2 + v3);
                acc1 += (u0 + u1) + (u2 + u3);
            }
            const float hval = ld_dev(hp + n * S + s);

            // ---- phases B+C: z|r gate (split across wave halves) + hh
            const float* __restrict__ W1 = g ? (sW + 4096) : sW;
            const float* __restrict__ U1 = g ? (sU + 1024) : sU;
            const float* __restrict__ Wh = sW + 8192;
            float accA = sB[g * 32 + s];
            float accB = 0.f;
            float hA = 0.f, hB = 0.f;
            #pragma unroll
            for (int e = 0; e < E; ++e) {
                const float src = (e < 2) ? acc0 : acc1;
                const float* w1c = W1 + e * 1024 + s;
                const float* whc = Wh + e * 1024 + s;
                #pragma unroll
                for (int k = 0; k < 32; k += 2) {
                    float a0 = rl(src, (e & 1) * 32 + k);
                    float a1 = rl(src, (e & 1) * 32 + k + 1);
                    accA = fmaf(a0, w1c[(k)     * 32], accA);
                    accB = fmaf(a1, w1c[(k + 1) * 32], accB);
                    hA   = fmaf(a0, whc[(k)     * 32], hA);
                    hB   = fmaf(a1, whc[(k + 1) * 32], hB);
                }
            }
            #pragma unroll
            for (int k = 0; k < 32; k += 2) {
                accA = fmaf(rl(hval, k),     U1[(k)     * 32 + s], accA);
                accB = fmaf(rl(hval, k + 1), U1[(k + 1) * 32 + s], accB);
            }
            const float zr  = fast_sigmoid(accA + accB);   // z (g=0) | r (g=1)
            const float r_s = __shfl(zr, 32 + s, 64);
            const float z_s = __shfl(zr, s, 64);
            const float rh  = r_s * hval;
            const float* __restrict__ Uh = sU + 2048;
            #pragma unroll
            for (int k = 0; k < 32; k += 2) {
                hA = fmaf(rl(rh, k),     Uh[(k)     * 32 + s], hA);
                hB = fmaf(rl(rh, k + 1), Uh[(k + 1) * 32 + s], hB);
            }
            const float hh   = fast_tanh(hA + hB);
            const float hnew = fmaf(z_s, hval - hh, hh);   // z*h + (1-z)*hh
            if (g == 0) st_dev(&hn[n * S + s], hnew);
            hlast = hnew;

            float* t = (float*)hp; hp = hn; hn = t;        // swap

            if (l != 2 || it != 4) {                       // no barrier after last iter
                gbar(p.bar, phase, b); phase++;
            }
        }
    }

    // ---- epilogue in-register: wave 5 of block 0 owns node 5 (h in hlast)
    if (b == 0 && wid == 5) {
        float y[5];
        #pragma unroll
        for (int j = 0; j < 5; ++j) y[j] = hlast * p.ow[s * 5 + j];
        #pragma unroll
        for (int off = 1; off < 32; off <<= 1) {
            #pragma unroll
            for (int j = 0; j < 5; ++j) y[j] += __shfl_xor(y[j], off, 64);
        }
        #pragma unroll
        for (int j = 0; j < 5; ++j) y[j] += p.ob[j];
        float m = -1e30f;
        #pragma unroll
        for (int j = 0; j < 5; ++j) m = fmaxf(m, y[j]);
        float ssum = 0.f;
        #pragma unroll
        for (int j = 0; j < 5; ++j) ssum += __expf(y[j] - m);
        float lse = m + __logf(ssum);
        #pragma unroll
        for (int j = 0; j < 5; ++j) if (lane == j) p.out[j] = y[j] - lse;
    }
}

// ---------------------------------------------------------------------------
// Fallback chain — launched by the HOST only if hipLaunchCooperativeKernel
// reports a (synchronous) rejection. Known-good round-3 structure.
// ---------------------------------------------------------------------------
__global__ __launch_bounds__(256) void init_h_fb(const float* __restrict__ x,
                                                 const float* __restrict__ fcw,
                                                 const float* __restrict__ fcb,
                                                 float* __restrict__ h0) {
    int t = blockIdx.x * 256 + threadIdx.x;
    int s = t & 31;
    int n = t >> 5;
    float acc = fcb[s];
    #pragma unroll 8
    for (int k = 0; k < FIN; ++k)
        acc = fmaf(x[n * FIN + k], fcw[k * S + s], acc);
    h0[n * S + s] = acc;
}

__global__ __launch_bounds__(512) void ggnn_iter_fb(
    const float* __restrict__ hprev, float* __restrict__ hnext,
    const int* __restrict__ deg, const int* __restrict__ csr,
    const float* __restrict__ wz, const float* __restrict__ wr, const float* __restrict__ wh,
    const float* __restrict__ uz, const float* __restrict__ ur, const float* __restrict__ uh,
    const float* __restrict__ bz, const float* __restrict__ br) {
    __shared__ __align__(16) float sWz[4096];
    __shared__ __align__(16) float sWr[4096];
    __shared__ __align__(16) float sWh[4096];
    __shared__ __align__(16) float sUz[1024], sUr[1024], sUh[1024];

    int tid = threadIdx.x;
    {
        float4*       dz = (float4*)sWz; const float4* gz = (const float4*)wz;
        float4*       dr = (float4*)sWr; const float4* gr = (const float4*)wr;
        float4*       dh = (float4*)sWh; const float4* gh = (const float4*)wh;
        for (int i = tid; i < 1024; i += 512) { dz[i] = gz[i]; dr[i] = gr[i]; dh[i] = gh[i]; }
        float4*       duz = (float4*)sUz; const float4* guz = (const float4*)uz;
        float4*       dur = (float4*)sUr; const float4* gur = (const float4*)ur;
        float4*       duh = (float4*)sUh; const float4* guh = (const float4*)uh;
        if (tid < 256) { duz[tid] = guz[tid]; dur[tid] = gur[tid]; duh[tid] = guh[tid]; }
    }
    __syncthreads();

    const int wid  = tid >> 6;
    const int lane = tid & 63;
    const int s    = lane & 31;
    const int g    = lane >> 5;
    const int n    = blockIdx.x * 8 + wid;

    const int d1 = min(deg[g * N + n], CAP);
    const int d2 = min(deg[(g + 2) * N + n], CAP);
    const int* __restrict__ l1 = csr + (g * N + n) * CAP;
    const int* __restrict__ l2 = csr + ((g + 2) * N + n) * CAP;
    float acc0 = 0.f, acc1 = 0.f;
    const int dmax = max(d1, d2);
    for (int i = 0; i < dmax; ++i) {
        if (i < d1) acc0 += hprev[l1[i] * S + s];
        if (i < d2) acc1 += hprev[l2[i] * S + s];
    }
    const float hval = hprev[n * S + s];

    const float* __restrict__ W1 = g ? sWr : sWz;
    const float* __restrict__ U1 = g ? sUr : sUz;
    float accA = g ? br[s] : bz[s];
    float accB = 0.f;
    float hA = 0.f, hB = 0.f;
    #pragma unroll
    for (int e = 0; e < E; ++e) {
        const float src = (e < 2) ? acc0 : acc1;
        const float* w1c = W1 + e * 1024 + s;
        const float* whc = sWh + e * 1024 + s;
        #pragma unroll
        for (int k = 0; k < 32; k += 2) {
            float a0 = rl(src, (e & 1) * 32 + k);
            float a1 = rl(src, (e & 1) * 32 + k + 1);
            accA = fmaf(a0, w1c[(k)     * 32], accA);
            accB = fmaf(a1, w1c[(k + 1) * 32], accB);
            hA   = fmaf(a0, whc[(k)     * 32], hA);
            hB   = fmaf(a1, whc[(k + 1) * 32], hB);
        }
    }
    #pragma unroll
    for (int k = 0; k < 32; k += 2) {
        accA = fmaf(rl(hval, k),     U1[(k)     * 32 + s], accA);
        accB = fmaf(rl(hval, k + 1), U1[(k + 1) * 32 + s], accB);
    }
    const float zr  = fast_sigmoid(accA + accB);
    const float r_s = __shfl(zr, 32 + s, 64);
    const float z_s = __shfl(zr, s, 64);
    const float rh  = r_s * hval;
    #pragma unroll
    for (int k = 0; k < 32; k += 2) {
        hA = fmaf(rl(rh, k),     sUh[(k)     * 32 + s], hA);
        hB = fmaf(rl(rh, k + 1), sUh[(k + 1) * 32 + s], hB);
    }
    const float hh = fast_tanh(hA + hB);
    const float hnew = fmaf(z_s, hval - hh, hh);
    if (g == 0) hnext[n * S + s] = hnew;
}

__global__ void epilogue_fb(const float* __restrict__ h,
                            const float* __restrict__ ow, const float* __restrict__ ob,
                            float* __restrict__ out) {
    int lane = threadIdx.x;
    float y = 0.f;
    if (lane < 5) {
        y = ob[lane];
        for (int k = 0; k < 32; ++k)
            y = fmaf(h[5 * S + k], ow[k * 5 + lane], y);
    }
    float m = -1e30f;
    #pragma unroll
    for (int j = 0; j < 5; ++j) m = fmaxf(m, __shfl(y, j, 64));
    float ssum = 0.f;
    #pragma unroll
    for (int j = 0; j < 5; ++j) ssum += __expf(__shfl(y, j, 64) - m);
    float lse = m + __logf(ssum);
    if (lane < 5) out[lane] = y - lse;
}

extern "C" void kernel_launch(void* const* d_in, const int* in_sizes, int n_in,
                              void* d_out, int out_size, void* d_ws, size_t ws_size,
                              hipStream_t stream) {
    const float* x     = (const float*)d_in[0];
    // d_in[1] = x_lengths (int32) — unused by the reference
    const float* edges = (const float*)d_in[2];
    const float* fcw   = (const float*)d_in[3];
    const float* fcb   = (const float*)d_in[4];
    const float* wz    = (const float*)d_in[5];
    const float* wr    = (const float*)d_in[6];
    const float* wh    = (const float*)d_in[7];
    const float* uz    = (const float*)d_in[8];
    const float* ur    = (const float*)d_in[9];
    const float* uh    = (const float*)d_in[10];
    const float* bz    = (const float*)d_in[11];
    const float* br    = (const float*)d_in[12];
    const float* ow    = (const float*)d_in[13];
    const float* ob    = (const float*)d_in[14];

    char* ws = (char*)d_ws;
    float* h0  = (float*)(ws);                   // 3073 rows * 32 * 4 = 393,344 B
    float* h1  = (float*)(ws + 393600);
    int*   deg = (int*)(ws + 787200);            // 49,152 B
    int*   bar = (int*)(ws + 836352);            // 2,048 B tree-barrier lines
    int*   csr = (int*)(ws + 838400);            // 3,145,728 B -> end 3,984,128

    // zero deg + barrier lines in one contiguous memset
    hipMemsetAsync(deg, 0, 49152 + 2048, stream);
    build_csr<<<36864, 256, 0, stream>>>(edges, deg, csr);

    Params p;
    p.x = x; p.fcw = fcw; p.fcb = fcb;
    p.wz = wz; p.wr = wr; p.wh = wh;
    p.uz = uz; p.ur = ur; p.uh = uh;
    p.bz = bz; p.br = br; p.ow = ow; p.ob = ob;
    p.deg = deg; p.csr = csr; p.bar = bar;
    p.h0 = h0; p.h1 = h1; p.out = (float*)d_out;

    void* args[] = { &p };
    hipError_t err = hipLaunchCooperativeKernel((const void*)fused_ggnn,
                                                dim3(BLK), dim3(TPB), args, 0, stream);
    if (err != hipSuccess) {
        // Launch rejected synchronously -> known-good multi-dispatch path.
        init_h_fb<<<384, 256, 0, stream>>>(x, fcw, fcb, h0);
        float* ha = h0;
        float* hb = h1;
        for (int l = 0; l < 3; ++l) {
            for (int it = 0; it < 5; ++it) {
                ggnn_iter_fb<<<384, 512, 0, stream>>>(ha, hb, deg, csr,
                    wz + l * 4096, wr + l * 4096, wh + l * 4096,
                    uz + l * 1024, ur + l * 1024, uh + l * 1024,
                    bz + l * 32, br + l * 32);
                float* t = ha; ha = hb; hb = t;
            }
        }
        epilogue_fb<<<1, 64, 0, stream>>>(ha, ow, ob, (float*)d_out);
    }
}